// Round 1
// 187.998 us; speedup vs baseline: 1.0005x; 1.0005x over previous
//
#include <hip/hip_runtime.h>
#include <math.h>

#define B_   128
#define T_   50
#define MI_  32
#define E_   128
#define EW_  16
#define D_   144
#define G_   432        // 3*D
#define N_   (B_*T_)    // 6400

// ---------------------------------------------------------------------------
// K1: basket embedding v2 — parallel gather.
// v1 had a SERIAL chain of <=32 conditional 512B loads per block (latency-
// bound).  v2: 256 threads/block; thread (i=tid>>3, j=tid&7) loads 64B of
// item i's row -> all 32 row-loads in flight at once.  Branch-free: the
// reference sets encode_w[0] = 0, so zero items contribute nothing to the
// sum; the divisor count is summed from flags.  Reduction through LDS with
// stride-132 padding: b128 stores land 8 accesses on every bank (the 1KB/
// 128B-per-cy structural minimum, perfectly balanced); the 32 b32 read
// rounds are exact 2-way aliasing (free per m136).
// ---------------------------------------------------------------------------
__global__ __launch_bounds__(256) void embed_kernel(
    const int* __restrict__ x,            // [N_][33]
    const float* __restrict__ encode_w,   // [100000][128]  (row 0 == 0)
    const float* __restrict__ wchange_w,  // [2][16]
    float* __restrict__ seq)              // [N_][144]
{
    int n = blockIdx.x;
    int tid = threadIdx.x;
    int i = tid >> 3;        // item 0..31
    int j = tid & 7;         // col chunk [16j, 16j+16)

    __shared__ int xi[33];
    __shared__ __align__(16) float part[32 * 132];  // stride 132 words
    __shared__ float cntf[32];

    if (tid < 33) xi[tid] = x[n * 33 + tid];
    __syncthreads();

    int it = xi[i];
    const float* row = &encode_w[(size_t)it * E_];
    // 4 x float4 = 64B of this item's row; all items' loads concurrent
    float4 v0 = *(const float4*)&row[16 * j + 0];
    float4 v1 = *(const float4*)&row[16 * j + 4];
    float4 v2 = *(const float4*)&row[16 * j + 8];
    float4 v3 = *(const float4*)&row[16 * j + 12];

    float* p = &part[i * 132 + 16 * j];
    *(float4*)&p[0]  = v0;
    *(float4*)&p[4]  = v1;
    *(float4*)&p[8]  = v2;
    *(float4*)&p[12] = v3;
    if (j == 0) cntf[i] = (it != 0) ? 1.f : 0.f;
    __syncthreads();

    if (tid < E_) {
        int c = tid;
        float s = 0.f, cn = 0.f;
        #pragma unroll
        for (int k = 0; k < 32; ++k) {
            s  += part[k * 132 + c];   // 2-way bank aliasing: free
            cn += cntf[k];             // broadcast: free
        }
        seq[n * D_ + c] = s / fmaxf(cn, 1.f);
    } else if (tid < E_ + EW_) {
        int c = tid - E_;
        seq[n * D_ + E_ + c] = wchange_w[xi[32] * EW_ + c];
    }
}

// ---------------------------------------------------------------------------
// K2/K4: C[M][N] = A[M][144] * Bw[N][144]^T + bias[N].  K fixed = 144.
// 64x64 tile, k-major LDS (pad 68 words -> conflict-free b128 reads), BK=48.
// ---------------------------------------------------------------------------
#define GK   144
#define GBK  48
#define GPAD 68

__global__ __launch_bounds__(256) void gemm_bias_kernel(
    const float* __restrict__ A,
    const float* __restrict__ Bw,
    const float* __restrict__ bias,
    float* __restrict__ C,
    int M, int N)
{
    __shared__ float As[GBK * GPAD];
    __shared__ float Bs[GBK * GPAD];

    int tid = threadIdx.x;
    int row0 = blockIdx.x * 64;
    int col0 = blockIdx.y * 64;
    int tx = tid & 15;        // col group
    int ty = tid >> 4;        // row group

    float acc[4][4] = {};

    int sr = tid >> 2;
    int skq0 = tid & 3;

    for (int k0 = 0; k0 < GK; k0 += GBK) {
        __syncthreads();
        #pragma unroll
        for (int i = 0; i < 3; ++i) {
            int kq = skq0 + i * 4;          // 0..11  (48 k / 4)
            float4 a = *(const float4*)&A[(size_t)(row0 + sr) * GK + k0 + kq * 4];
            int nrow = col0 + sr;
            float4 b = make_float4(0.f, 0.f, 0.f, 0.f);
            if (nrow < N)
                b = *(const float4*)&Bw[(size_t)nrow * GK + k0 + kq * 4];
            As[(kq * 4 + 0) * GPAD + sr] = a.x;
            As[(kq * 4 + 1) * GPAD + sr] = a.y;
            As[(kq * 4 + 2) * GPAD + sr] = a.z;
            As[(kq * 4 + 3) * GPAD + sr] = a.w;
            Bs[(kq * 4 + 0) * GPAD + sr] = b.x;
            Bs[(kq * 4 + 1) * GPAD + sr] = b.y;
            Bs[(kq * 4 + 2) * GPAD + sr] = b.z;
            Bs[(kq * 4 + 3) * GPAD + sr] = b.w;
        }
        __syncthreads();

        #pragma unroll 4
        for (int k = 0; k < GBK; ++k) {
            float4 a4 = *(const float4*)&As[k * GPAD + ty * 4];
            float4 b4 = *(const float4*)&Bs[k * GPAD + tx * 4];
            float av[4] = {a4.x, a4.y, a4.z, a4.w};
            float bv[4] = {b4.x, b4.y, b4.z, b4.w};
            #pragma unroll
            for (int i = 0; i < 4; ++i)
                #pragma unroll
                for (int j = 0; j < 4; ++j)
                    acc[i][j] = fmaf(av[i], bv[j], acc[i][j]);
        }
    }

    int c = col0 + tx * 4;
    if (c < N) {
        float4 bb = *(const float4*)&bias[c];
        #pragma unroll
        for (int i = 0; i < 4; ++i) {
            int r = row0 + ty * 4 + i;
            float4 o;
            o.x = acc[i][0] + bb.x;
            o.y = acc[i][1] + bb.y;
            o.z = acc[i][2] + bb.z;
            o.w = acc[i][3] + bb.w;
            *(float4*)&C[(size_t)r * N + c] = o;
        }
    }
}

// ---------------------------------------------------------------------------
// K3: GRU v4 — gate-triple row mapping + register elementwise.
// v3 (54.3 us measured): rows 6g..6g+5 per group -> after DPP butterfly the
// 3 gate values of one h-element live in 3 DIFFERENT groups -> gh round-trip
// through LDS + a second barrier; VALUBusy 27%, latency-bound.
// v4: group g owns rows {2g,2g+1, 144+2g,144+2g+1, 288+2g,288+2g+1} (the
// r/z/n triples of elements 2g,2g+1).  The butterfly leaves ALL 8 lanes of
// the group holding all 6 sums, so lane s<2 has the complete r/z/n dots for
// element 2g+s IN REGISTERS: elementwise runs immediately, no gh LDS write,
// no gather, no cndmask select chain.  h double-buffered (h[2][160]) ->
// exactly ONE __syncthreads per step (write->read); the read->write hazard
// is gone because write targets the other buffer.  gi prefetched one full
// step ahead (~1.5 steps of latency cover, L2/L3-resident).
// Per-row arithmetic order (20-chunk partials, same butterfly, bias added
// after reduction) is bit-identical to v3 -> absmax unchanged.
// ---------------------------------------------------------------------------
template<int CTRL>
__device__ __forceinline__ float dpp_xor_add(float x) {
    int y = __builtin_amdgcn_mov_dpp(__float_as_int(x), CTRL, 0xF, 0xF, true);
    return x + __int_as_float(y);
}

__global__ __launch_bounds__(576) void gru_kernel(
    const float* __restrict__ gi,     // [N_][432]
    const float* __restrict__ w_hh,   // [432][144]
    const float* __restrict__ b_hh,   // [432]
    const float* __restrict__ h0,     // [128][144]
    float* __restrict__ hseq,         // [N_][144]
    float* __restrict__ hlast)        // [128][144]
{
    int b = blockIdx.x;
    int tid = threadIdx.x;
    int g = tid >> 3;       // 0..71  -> elements 2g, 2g+1
    int s = tid & 7;        // k-chunk [20s, 20s+20)
    int k0 = s * 20;
    int e = 2 * g + (s & 1);      // element owned by active lanes (s<2)

    __shared__ __align__(16) float hb[2][160];   // double-buffered h, k-padded

    // weights into VGPRs: row r -> gate (r>>1), element 2g+(r&1)
    float w[6][20];
    #pragma unroll
    for (int r = 0; r < 6; ++r) {
        int rowi = (r >> 1) * D_ + 2 * g + (r & 1);
        const float* wrow = &w_hh[(size_t)rowi * D_];
        #pragma unroll
        for (int q = 0; q < 5; ++q) {
            int k = k0 + 4 * q;
            float4 t = make_float4(0.f, 0.f, 0.f, 0.f);
            if (k < D_) t = *(const float4*)&wrow[k];   // k<=140, safe
            w[r][4 * q + 0] = t.x;
            w[r][4 * q + 1] = t.y;
            w[r][4 * q + 2] = t.z;
            w[r][4 * q + 3] = t.w;
        }
    }
    float br = 0.f, bz = 0.f, bn = 0.f;
    if (s < 2) {
        br = b_hh[e];
        bz = b_hh[D_ + e];
        bn = b_hh[2 * D_ + e];
    }

    if (tid < 160) {
        hb[0][tid] = (tid < D_) ? h0[b * D_ + tid] : 0.f;
        hb[1][tid] = 0.f;                 // pad region of both buffers stays 0
    }
    __syncthreads();

    // gi prefetch registers (one step ahead)
    float gir = 0.f, giz = 0.f, ginv = 0.f;
    if (s < 2) {
        const float* gp = &gi[(size_t)(b * T_) * G_];
        gir  = gp[e];
        giz  = gp[D_ + e];
        ginv = gp[2 * D_ + e];
    }

    int cur = 0;
    float hn_last = 0.f;
    for (int t = 0; t < T_; ++t) {
        int n = b * T_ + t;

        // consume this step's prefetched gi; immediately issue next step's
        float girU = gir, gizU = giz, ginU = ginv;
        float hold = 0.f;
        if (s < 2) {
            hold = hb[cur][e];
            if (t + 1 < T_) {
                const float* gp = &gi[(size_t)(n + 1) * G_];
                gir  = gp[e];
                giz  = gp[D_ + e];
                ginv = gp[2 * D_ + e];
            }
        }

        // h chunk: 5 conflict-free ds_read_b128 (8-way broadcast across groups)
        float hv[20];
        #pragma unroll
        for (int q = 0; q < 5; ++q) {
            float4 t4 = *(const float4*)&hb[cur][k0 + 4 * q];
            hv[4 * q + 0] = t4.x;
            hv[4 * q + 1] = t4.y;
            hv[4 * q + 2] = t4.z;
            hv[4 * q + 3] = t4.w;
        }

        // 6 rows x 20 k partial dots (120 fmac, 6 independent chains)
        float a0 = 0.f, a1 = 0.f, a2 = 0.f, a3 = 0.f, a4 = 0.f, a5 = 0.f;
        #pragma unroll
        for (int kk = 0; kk < 20; ++kk) {
            float hk = hv[kk];
            a0 = fmaf(w[0][kk], hk, a0);
            a1 = fmaf(w[1][kk], hk, a1);
            a2 = fmaf(w[2][kk], hk, a2);
            a3 = fmaf(w[3][kk], hk, a3);
            a4 = fmaf(w[4][kk], hk, a4);
            a5 = fmaf(w[5][kk], hk, a5);
        }

        // butterfly across the 8 k-chunk lanes: ALL lanes end with full sums
        a0 = dpp_xor_add<0xB1>(a0); a0 = dpp_xor_add<0x4E>(a0); a0 = dpp_xor_add<0x141>(a0);
        a1 = dpp_xor_add<0xB1>(a1); a1 = dpp_xor_add<0x4E>(a1); a1 = dpp_xor_add<0x141>(a1);
        a2 = dpp_xor_add<0xB1>(a2); a2 = dpp_xor_add<0x4E>(a2); a2 = dpp_xor_add<0x141>(a2);
        a3 = dpp_xor_add<0xB1>(a3); a3 = dpp_xor_add<0x4E>(a3); a3 = dpp_xor_add<0x141>(a3);
        a4 = dpp_xor_add<0xB1>(a4); a4 = dpp_xor_add<0x4E>(a4); a4 = dpp_xor_add<0x141>(a4);
        a5 = dpp_xor_add<0xB1>(a5); a5 = dpp_xor_add<0x4E>(a5); a5 = dpp_xor_add<0x141>(a5);

        // lane s<2: full r/z/n dots for element e=2g+s are in registers
        if (s < 2) {
            float ar = (s == 0) ? a0 : a1;
            float az = (s == 0) ? a2 : a3;
            float an = (s == 0) ? a4 : a5;
            float ghr = ar + br;                  // same order as v3: dot+bias
            float ghz = az + bz;
            float ghn = an + bn;
            float rr = 1.f / (1.f + __expf(-(girU + ghr)));
            float zz = 1.f / (1.f + __expf(-(gizU + ghz)));
            float narg = ginU + rr * ghn;
            narg = fminf(fmaxf(narg, -15.f), 15.f);
            float e2 = __expf(-2.f * narg);
            float nn = (1.f - e2) / (1.f + e2);
            float hn = (1.f - zz) * nn + zz * hold;
            hseq[(size_t)n * D_ + e] = hn;
            hb[cur ^ 1][e] = hn;
            hn_last = hn;
        }
        __syncthreads();          // the ONE barrier: h[next] ready for all
        cur ^= 1;
    }

    if (s < 2) hlast[b * D_ + e] = hn_last;
}

// ---------------------------------------------------------------------------
extern "C" void kernel_launch(void* const* d_in, const int* in_sizes, int n_in,
                              void* d_out, int out_size, void* d_ws, size_t ws_size,
                              hipStream_t stream)
{
    const int*   x         = (const int*)d_in[0];
    // d_in[1] = lengths (unused by the reference computation)
    const float* hidden    = (const float*)d_in[2];
    const float* encode_w  = (const float*)d_in[3];
    const float* wchange_w = (const float*)d_in[4];
    const float* w_ih      = (const float*)d_in[5];
    const float* w_hh      = (const float*)d_in[6];
    const float* b_ih      = (const float*)d_in[7];
    const float* b_hh      = (const float*)d_in[8];
    const float* fc_w      = (const float*)d_in[9];
    const float* fc_b      = (const float*)d_in[10];

    float* out = (float*)d_out;              // [N_][128] then [128][144]
    float* ws  = (float*)d_ws;
    float* seq  = ws;                        //   921600 floats
    float* gi   = ws + 921600;               //  2764800 floats
    float* hseq = ws + 921600 + 2764800;     //   921600 floats  (18.4 MB total)

    // K1: embedding (parallel gather v2)
    embed_kernel<<<N_, 256, 0, stream>>>(x, encode_w, wchange_w, seq);

    // K2: gi = seq @ w_ih^T + b_ih   (M=6400, N=432)
    gemm_bias_kernel<<<dim3(N_ / 64, (G_ + 63) / 64), 256, 0, stream>>>(
        seq, w_ih, b_ih, gi, N_, G_);

    // K3: GRU over T=50 (v4: triple-mapped rows, 1 barrier/step)
    gru_kernel<<<B_, 576, 0, stream>>>(gi, w_hh, b_hh, hidden, hseq,
                                       out + (size_t)N_ * E_);

    // K4: dynamic_user = hseq @ fc_w^T + fc_b   (M=6400, N=128)
    gemm_bias_kernel<<<dim3(N_ / 64, E_ / 64), 256, 0, stream>>>(
        hseq, fc_w, fc_b, out, N_, E_);
}